// Round 18
// baseline (394.154 us; speedup 1.0000x reference)
//
#include <hip/hip_runtime.h>

typedef __attribute__((ext_vector_type(8))) short short8v;
typedef __attribute__((ext_vector_type(8))) unsigned short ushort8v;
typedef __attribute__((ext_vector_type(4))) float float4v;

__device__ __constant__ float c_LO[8] = {
    -0.010597401784997278f, 0.032883011666982945f, 0.030841381835986965f,
    -0.18703481171888114f, -0.02798376941698385f, 0.6308807679295904f,
    0.7148465705525415f, 0.23037781330885523f};
__device__ __constant__ float c_HI[8] = {
    -0.23037781330885523f, 0.7148465705525415f, -0.6308807679295904f,
    -0.02798376941698385f, 0.18703481171888114f, 0.030841381835986965f,
    -0.032883011666982945f, -0.010597401784997278f};

__device__ __forceinline__ unsigned short f2bf(float f) {
    unsigned u = __builtin_bit_cast(unsigned, f);
    unsigned r = u + 0x7fffu + ((u >> 16) & 1u);
    return (unsigned short)(r >> 16);
}
__device__ __forceinline__ float bf2f(unsigned short u) {
    return __builtin_bit_cast(float, (unsigned)u << 16);
}

__device__ __forceinline__ float gelu_fast(float x) {
    float x3 = x * x * x;
    float y = fmaf(0.044715f, x3, x) * 0.7978845608028654f;
    float t = fminf(fmaxf(y * 2.8853900817779268f, -30.f), 30.f);
    float e = exp2f(t);
    return x * e * __builtin_amdgcn_rcpf(e + 1.0f);
}

__device__ __forceinline__ void gload_lds16(const void* g, void* l) {
    __builtin_amdgcn_global_load_lds(g, l, 16, 0, 0);
}

// ---- one DWT level helpers (pywt symmetric) ----
__device__ __forceinline__ void dwt_lvl(const float* __restrict__ in, int n, float* __restrict__ outA,
                                        unsigned short* __restrict__ outD, int m, int lane) {
    for (int j = lane; j < m; j += 64) {
        float a = 0.f, d = 0.f;
#pragma unroll
        for (int i = 0; i < 8; ++i) {
            int p = 2 * j + 7 - i;
            int q = (p < 6) ? (5 - p) : ((p < n + 6) ? (p - 6) : (2 * n + 5 - p));
            float xv = in[q];
            a = fmaf(c_LO[i], xv, a);
            d = fmaf(c_HI[i], xv, d);
        }
        outA[j] = a;
        outD[j] = f2bf(d);
    }
}
__device__ __forceinline__ void dwt_lvl_final(const float* __restrict__ in, int n, unsigned short* __restrict__ outA,
                                              unsigned short* __restrict__ outD, int m, int lane) {
    for (int j = lane; j < m; j += 64) {
        float a = 0.f, d = 0.f;
#pragma unroll
        for (int i = 0; i < 8; ++i) {
            int p = 2 * j + 7 - i;
            int q = (p < 6) ? (5 - p) : ((p < n + 6) ? (p - 6) : (2 * n + 5 - p));
            float xv = in[q];
            a = fmaf(c_LO[i], xv, a);
            d = fmaf(c_HI[i], xv, d);
        }
        outA[j] = f2bf(a);
        outD[j] = f2bf(d);
    }
}

struct Bounds { int b[6]; };

// ---- pack helpers (LDS-tiled transpose, both sides coalesced) ----
__device__ __forceinline__ void job_pack_w(const float* __restrict__ W, unsigned short* __restrict__ WT,
                                           int br, int k0, int n0, int K, int N, int Kpad,
                                           float (*t)[65], int tid) {
#pragma unroll
    for (int i = 0; i < 16; ++i) {
        int idx = tid + i * 256;
        int kk = idx >> 6, nn = idx & 63;
        int k = k0 + kk;
        t[kk][nn] = (k < K) ? W[((size_t)br * K + k) * N + n0 + nn] : 0.f;
    }
    __syncthreads();
#pragma unroll
    for (int i = 0; i < 16; ++i) {
        int idx = tid + i * 256;
        int nn = idx >> 6, kk = idx & 63;
        int k = k0 + kk;
        if (k < Kpad)
            WT[((size_t)br * N + n0 + nn) * Kpad + k] = f2bf(t[kk][nn]);
    }
}

__device__ __forceinline__ void job_pack_basis(const float* __restrict__ basis, unsigned short* __restrict__ BT,
                                               Bounds bd, int brows, int N, int K, int Kpad,
                                               int k0, int n0, float (*t)[65], int tid) {
#pragma unroll
    for (int i = 0; i < 16; ++i) {
        int idx = tid + i * 256;
        int kk = idx >> 6, nn = idx & 63;
        int k = k0 + kk;
        float v = 0.f;
        if (k < K) {
            int s = 0;
#pragma unroll
            for (int u = 1; u < 5; ++u)
                if (k >= bd.b[u]) s = u;
            int lr = k - bd.b[s];
            v = basis[((size_t)s * brows + lr) * N + n0 + nn];
        }
        t[kk][nn] = v;
    }
    __syncthreads();
#pragma unroll
    for (int i = 0; i < 16; ++i) {
        int idx = tid + i * 256;
        int nn = idx >> 6, kk = idx & 63;
        int k = k0 + kk;
        if (k < Kpad)
            BT[(size_t)(n0 + nn) * Kpad + k] = f2bf(t[kk][nn]);
    }
}

// ---- MEGA-PREP: all packs + wavedec(x) + CSR histogram in ONE kernel ----
__global__ __launch_bounds__(256) void prep_kernel(const float* __restrict__ x,
                                                   const float* __restrict__ basisenc,
                                                   const float* __restrict__ basisdec,
                                                   const float* __restrict__ Wd_enc,
                                                   const float* __restrict__ Wd_dec,
                                                   const float* __restrict__ W_mu,
                                                   const float* __restrict__ W_lv,
                                                   const int* __restrict__ arows, int E,
                                                   unsigned short* __restrict__ cenc,
                                                   unsigned short* __restrict__ BceT,
                                                   unsigned short* __restrict__ BcdT,
                                                   unsigned short* __restrict__ WdencT,
                                                   unsigned short* __restrict__ WddecT,
                                                   unsigned short* __restrict__ WmuT,
                                                   unsigned short* __restrict__ WlvT,
                                                   int* __restrict__ csr_cnt) {
    __shared__ __align__(16) char smem[18688];
    const int bid = blockIdx.x;
    const int tid = threadIdx.x;
    float (*t)[65] = (float(*)[65])smem;

    if (bid < 104) {
        Bounds be = {{0, 54, 108, 210, 407, 794}};
        int b = bid;
        job_pack_basis(basisenc, BceT, be, 768, 512, 794, 800, (b % 13) * 64, (b / 13) * 64, t, tid);
    } else if (bid < 212) {
        Bounds bdd = {{0, 38, 76, 146, 279, 538}};
        int b = bid - 104;
        job_pack_basis(basisdec, BcdT, bdd, 512, 768, 538, 544, (b % 9) * 64, (b / 9) * 64, t, tid);
    } else if (bid < 852) {
        int b = bid - 212;
        int br = b / 32, rem = b % 32;
        job_pack_w(Wd_enc, WdencT, br, (rem % 8) * 64, (rem / 8) * 64, 512, 256, 512, t, tid);
    } else if (bid < 1492) {
        int b = bid - 852;
        int br = b / 32, rem = b % 32;
        job_pack_w(Wd_dec, WddecT, br, (rem % 4) * 64, (rem / 4) * 64, 256, 512, 256, t, tid);
    } else if (bid < 1508) {
        int b = bid - 1492;
        job_pack_w(W_mu, WmuT, 0, (b % 4) * 64, (b / 4) * 64, 256, 256, 256, t, tid);
    } else if (bid < 1524) {
        int b = bid - 1508;
        job_pack_w(W_lv, WlvT, 0, (b % 4) * 64, (b / 4) * 64, 256, 256, 256, t, tid);
    } else if (bid < 5620) {
        const int widx = tid >> 6, lane = tid & 63;
        const int r = (bid - 1524) * 4 + widx;
        float* b0 = (float*)smem + widx * 1168;
        float* b1 = b0 + 768;
        const float* ip = x + (size_t)r * 768;
        for (int i = lane; i < 768; i += 64) b0[i] = ip[i];
        __syncthreads();
        unsigned short* cr = cenc + (size_t)r * 800;
        dwt_lvl(b0, 768, b1, cr + 407, 387, lane);
        __syncthreads();
        dwt_lvl(b1, 387, b0, cr + 210, 197, lane);
        __syncthreads();
        dwt_lvl(b0, 197, b1, cr + 108, 102, lane);
        __syncthreads();
        dwt_lvl_final(b1, 102, cr + 0, cr + 54, 54, lane);
        if (lane < 6) cr[794 + lane] = 0;
    } else {
        int i = (bid - 5620) * 256 + tid;
        if (i < E) atomicAdd(&csr_cnt[arows[i]], 1);
    }
}

// ---------------- CSR build (scan + scatter) ----------------
__global__ __launch_bounds__(1024) void scan_kernel(const int* __restrict__ cnt, int* __restrict__ offs,
                                                    int* __restrict__ cursor, int Nrows, int E) {
    __shared__ int part[1024];
    int tid = threadIdx.x;
    const int per = Nrows / 1024;  // 16
    int base = tid * per;
    int local[16];
    int s = 0;
    for (int i = 0; i < per; ++i) { local[i] = s; s += cnt[base + i]; }
    part[tid] = s;
    __syncthreads();
    for (int off = 1; off < 1024; off <<= 1) {
        int v = part[tid];
        int w = (tid >= off) ? part[tid - off] : 0;
        __syncthreads();
        part[tid] = v + w;
        __syncthreads();
    }
    int pre = (tid == 0) ? 0 : part[tid - 1];
    for (int i = 0; i < per; ++i) {
        int o = pre + local[i];
        offs[base + i] = o;
        cursor[base + i] = o;
    }
    if (tid == 0) offs[Nrows] = E;
}

__global__ void scatter_kernel(const int* __restrict__ rows, const int* __restrict__ cols,
                               const float* __restrict__ vals, int* __restrict__ cursor,
                               int* __restrict__ ccol, float* __restrict__ cval, int E) {
    int i = blockIdx.x * blockDim.x + threadIdx.x;
    if (i >= E) return;
    int r = rows[i];
    int p = atomicAdd(&cursor[r], 1);
    ccol[p] = cols[i];
    cval[p] = vals[i];
}

// ---- FUSED SpMM gather + LayerNorm -> hbf bf16; 4-wide gather pipeline ----
__global__ __launch_bounds__(256) void spmm_ln(const unsigned short* __restrict__ hx,
                                               const int* __restrict__ offs,
                                               const int* __restrict__ ccol,
                                               const float* __restrict__ cval,
                                               const float* __restrict__ g,
                                               const float* __restrict__ b,
                                               unsigned short* __restrict__ hbf) {
    const int widx = threadIdx.x >> 6, lane = threadIdx.x & 63;
    const int r = blockIdx.x * 4 + widx;
    int s = offs[r], e = offs[r + 1];
    float a0[8] = {}, a1[8] = {}, a2[8] = {}, a3[8] = {};
    int j = s;
    for (; j + 3 < e; j += 4) {
        int c0 = ccol[j], c1 = ccol[j + 1], c2 = ccol[j + 2], c3 = ccol[j + 3];
        float v0 = cval[j], v1 = cval[j + 1], v2 = cval[j + 2], v3 = cval[j + 3];
        ushort8v u0 = *(const ushort8v*)(hx + (size_t)c0 * 512 + lane * 8);
        ushort8v u1 = *(const ushort8v*)(hx + (size_t)c1 * 512 + lane * 8);
        ushort8v u2 = *(const ushort8v*)(hx + (size_t)c2 * 512 + lane * 8);
        ushort8v u3 = *(const ushort8v*)(hx + (size_t)c3 * 512 + lane * 8);
#pragma unroll
        for (int t = 0; t < 8; ++t) {
            a0[t] = fmaf(v0, bf2f(u0[t]), a0[t]);
            a1[t] = fmaf(v1, bf2f(u1[t]), a1[t]);
            a2[t] = fmaf(v2, bf2f(u2[t]), a2[t]);
            a3[t] = fmaf(v3, bf2f(u3[t]), a3[t]);
        }
    }
    for (; j < e; ++j) {
        int c0 = ccol[j];
        float v0 = cval[j];
        ushort8v u0 = *(const ushort8v*)(hx + (size_t)c0 * 512 + lane * 8);
#pragma unroll
        for (int t = 0; t < 8; ++t) a0[t] = fmaf(v0, bf2f(u0[t]), a0[t]);
    }
    float acc[8];
#pragma unroll
    for (int t = 0; t < 8; ++t) acc[t] = (a0[t] + a1[t]) + (a2[t] + a3[t]);

    float s1 = 0.f, s2 = 0.f;
#pragma unroll
    for (int t = 0; t < 8; ++t) { s1 += acc[t]; s2 = fmaf(acc[t], acc[t], s2); }
#pragma unroll
    for (int off = 32; off >= 1; off >>= 1) {
        s1 += __shfl_xor(s1, off);
        s2 += __shfl_xor(s2, off);
    }
    float mean = s1 * (1.f / 512.f);
    float var = s2 * (1.f / 512.f) - mean * mean;
    float inv = rsqrtf(var + 1e-5f);
    ushort8v o;
#pragma unroll
    for (int t = 0; t < 8; ++t) {
        int col = lane * 8 + t;
        o[t] = f2bf((acc[t] - mean) * inv * g[col] + b[col]);
    }
    *(ushort8v*)(hbf + (size_t)r * 512 + lane * 8) = o;
}

// ---- FUSED: 4-level wavedec of dec (bf16 in) -> cdec bf16 [N,544] ----
__global__ __launch_bounds__(256) void wavedec_dec(const unsigned short* __restrict__ decb,
                                                   unsigned short* __restrict__ cdec) {
    __shared__ float buf0[4][512];
    __shared__ float buf1[4][272];
    const int widx = threadIdx.x >> 6, lane = threadIdx.x & 63;
    const int r = blockIdx.x * 4 + widx;
    float* b0 = buf0[widx];
    float* b1 = buf1[widx];
    const unsigned short* ip = decb + (size_t)r * 512;
    for (int i = lane; i < 512; i += 64) b0[i] = bf2f(ip[i]);
    __syncthreads();
    unsigned short* cr = cdec + (size_t)r * 544;
    dwt_lvl(b0, 512, b1, cr + 279, 259, lane);
    __syncthreads();
    dwt_lvl(b1, 259, b0, cr + 146, 133, lane);
    __syncthreads();
    dwt_lvl(b0, 133, b1, cr + 76, 70, lane);
    __syncthreads();
    dwt_lvl_final(b1, 70, cr + 0, cr + 38, 38, lane);
    if (lane < 6) cr[538 + lane] = 0;
}

// ---------------- bf16 MFMA GEMM: double-buffered 2-phase (prefetch-before-compute) ----------------
// MODE 0: f32 out. MODE 1: bf16 out. MODE 2: mu/lv split epilogue.
template <int MODE>
__global__ __launch_bounds__(256) void gemm_mfma(const unsigned short* __restrict__ A,
                                                 const unsigned short* __restrict__ BT,
                                                 const float* __restrict__ bias,
                                                 const float* __restrict__ bias2,
                                                 void* __restrict__ Cv, void* __restrict__ Cv2,
                                                 int M, int N, int K, int lda, int ldb, int ldc, int nx) {
    __shared__ __align__(16) unsigned short As[2 * 128 * 32];
    __shared__ __align__(16) unsigned short Bs[2 * 128 * 32];
    const int tid = threadIdx.x;
    const int wave = tid >> 6, lane = tid & 63;
    const int nwg = gridDim.x;
    const int logical = (blockIdx.x & 7) * (nwg >> 3) + (blockIdx.x >> 3);
    const int mblk = logical / nx, nblk = logical - mblk * nx;
    const int m0 = mblk * 128, n0 = nblk * 128;
    const int wr = wave >> 1, wc = wave & 1;
    const int frow = lane & 15, fq = lane >> 4;

    const int off0 = tid * 16;
    const int r0 = off0 >> 6, c0 = off0 & 63;
    const int r1 = (off0 + 4096) >> 6, c1 = (off0 + 4096) & 63;
    const char* Ab = (const char*)A;
    const char* Bb = (const char*)BT;
    size_t gA0 = (size_t)(m0 + r0) * lda * 2 + c0;
    size_t gA1 = (size_t)(m0 + r1) * lda * 2 + c1;
    size_t gB0 = (size_t)(n0 + r0) * ldb * 2 + c0;
    size_t gB1 = (size_t)(n0 + r1) * ldb * 2 + c1;

    const int aoff = (wr * 64 + frow) * 32 + fq * 8;
    const int boff = (wc * 64 + frow) * 32 + fq * 8;
    const int KS = K >> 5;

    auto stage = [&](int ks, int buf) {
        size_t kb2 = (size_t)ks * 64;  // ks*32 elems * 2B
        char* lA = (char*)As + buf * 8192 + wave * 1024;
        char* lB = (char*)Bs + buf * 8192 + wave * 1024;
        gload_lds16(Ab + gA0 + kb2, lA);
        gload_lds16(Ab + gA1 + kb2, lA + 4096);
        gload_lds16(Bb + gB0 + kb2, lB);
        gload_lds16(Bb + gB1 + kb2, lB + 4096);
    };

    stage(0, 0);
    __syncthreads();
    float4v acc[4][4] = {};
    int buf = 0;
    for (int ks = 0; ks < KS; ++ks) {
        if (ks + 1 < KS) stage(ks + 1, buf ^ 1);
        const unsigned short* Ap = As + buf * 4096;
        const unsigned short* Bp = Bs + buf * 4096;
        short8v av[4], bv[4];
#pragma unroll
        for (int i = 0; i < 4; ++i) av[i] = *(const short8v*)(Ap + aoff + i * 512);
#pragma unroll
        for (int i = 0; i < 4; ++i) bv[i] = *(const short8v*)(Bp + boff + i * 512);
#pragma unroll
        for (int mi = 0; mi < 4; ++mi)
#pragma unroll
            for (int ni = 0; ni < 4; ++ni)
                acc[mi][ni] = __builtin_amdgcn_mfma_f32_16x16x32_bf16(av[mi], bv[ni], acc[mi][ni], 0, 0, 0);
        __syncthreads();
        buf ^= 1;
    }
#pragma unroll
    for (int ni = 0; ni < 4; ++ni) {
        int col = n0 + wc * 64 + ni * 16 + frow;
#pragma unroll
        for (int mi = 0; mi < 4; ++mi) {
#pragma unroll
            for (int i = 0; i < 4; ++i) {
                int row = m0 + wr * 64 + mi * 16 + fq * 4 + i;
                if (MODE == 0) {
                    ((float*)Cv)[(size_t)row * ldc + col] = acc[mi][ni][i];
                } else if (MODE == 1) {
                    ((unsigned short*)Cv)[(size_t)row * ldc + col] = f2bf(acc[mi][ni][i]);
                } else {
                    bool isMu = col < 256;
                    int coll = col & 255;
                    float bval = isMu ? bias[coll] : bias2[coll];
                    float* dst = (float*)(isMu ? Cv : Cv2);
                    dst[(size_t)row * 256 + coll] = acc[mi][ni][i] + bval;
                }
            }
        }
    }
}

// ---------------- z = mu + eps * exp(0.5*logvar)  -> bf16 ----------------
__global__ void z_kernel(const float* __restrict__ mu, const float* __restrict__ lv,
                         const float* __restrict__ eps, unsigned short* __restrict__ z, int n4) {
    int i = blockIdx.x * blockDim.x + threadIdx.x;
    if (i >= n4) return;
    float4 m = ((const float4*)mu)[i];
    float4 l = ((const float4*)lv)[i];
    float4 e = ((const float4*)eps)[i];
    ushort4 o;
    o.x = f2bf(m.x + e.x * expf(0.5f * l.x));
    o.y = f2bf(m.y + e.y * expf(0.5f * l.y));
    o.z = f2bf(m.z + e.z * expf(0.5f * l.z));
    o.w = f2bf(m.w + e.w * expf(0.5f * l.w));
    ((ushort4*)z)[i] = o;
}

// ---- dendritic enc (K=512): dual-branch, all 20 branches, DOUBLE-BUFFERED 2-phase ----
// Flattened 80-step loop: t = pair*8 + ks; stage(t+1) issued before compute(t); one barrier/step.
__global__ __launch_bounds__(256, 2) void dendritic_full(const unsigned short* __restrict__ A,
                                                         const unsigned short* __restrict__ WT,
                                                         const float* __restrict__ bias,
                                                         unsigned short* __restrict__ out,
                                                         int M, int Nc, int K, int nb, int nx) {
    __shared__ __align__(16) unsigned short As[2 * 128 * 64];   // 2 x 16 KB
    __shared__ __align__(16) unsigned short Bs[2][2][64 * 64];  // [buf][branch] 2x2x8 KB
    const int tid = threadIdx.x;
    const int wave = tid >> 6;
    const int lane = tid & 63;

    const int nwg = gridDim.x;
    const int logical = (blockIdx.x & 7) * (nwg >> 3) + (blockIdx.x >> 3);
    const int mblk = logical / nx;
    const int nblk = logical - mblk * nx;
    const int n0 = nblk * 64, m0 = mblk * 128;

    const int wr = wave >> 1, wc = wave & 1;
    const int frow = lane & 15, fq = lane >> 4;

    int srA[4], scA[4];
#pragma unroll
    for (int i = 0; i < 4; ++i) {
        int ch = i * 256 + tid;
        srA[i] = ch >> 3;
        scA[i] = ((ch & 7) ^ (srA[i] & 7)) * 16;
    }
    int srB[2], scB[2];
#pragma unroll
    for (int i = 0; i < 2; ++i) {
        int ch = i * 256 + tid;
        srB[i] = ch >> 3;
        scB[i] = ((ch & 7) ^ (srB[i] & 7)) * 16;
    }
    const char* Ab = (const char*)A;
    const size_t K2 = (size_t)K * 2;
    const size_t branchBytes = (size_t)Nc * K2;
    const int KS = K >> 6;             // 8 K-steps per branch
    const int T = (nb >> 1) * KS;      // 80 total steps

    auto stage = [&](int t, int buf) {
        int pr = t / KS, ks = t - pr * KS;
        size_t kby = (size_t)ks * 128;  // ks*64 elems * 2B
        const char* Bb0 = (const char*)WT + (size_t)(2 * pr) * branchBytes;
        const char* Bb1 = (const char*)WT + (size_t)(2 * pr + 1) * branchBytes;
        char* lA  = (char*)As + buf * 16384 + wave * 1024;
        char* lB0 = (char*)&Bs[buf][0][0] + wave * 1024;
        char* lB1 = (char*)&Bs[buf][1][0] + wave * 1024;
#pragma unroll
        for (int i = 0; i < 4; ++i)
            gload_lds16(Ab + (size_t)(m0 + srA[i]) * K2 + kby + scA[i], lA + i * 4096);
#pragma unroll
        for (int i = 0; i < 2; ++i)
            gload_lds16(Bb0 + (size_t)(n0 + srB[i]) * K2 + kby + scB[i], lB0 + i * 4096);
#pragma unroll
        for (int i = 0; i < 2; ++i)
            gload_lds16(Bb1 + (size_t)(n0 + srB[i]) * K2 + kby + scB[i], lB1 + i * 4096);
    };

    float4v hmn[4][2], hmx[4][2];
#pragma unroll
    for (int mi = 0; mi < 4; ++mi)
#pragma unroll
        for (int ni = 0; ni < 2; ++ni) { hmn[mi][ni] = (float4v)(1e30f); hmx[mi][ni] = (float4v)(-1e30f); }

    float4v ac0[4][2], ac1[4][2];
    stage(0, 0);
    __syncthreads();
    int buf = 0;
    for (int t = 0; t < T; ++t) {
        const int pr = t / KS, ks = t - pr * KS;
        if (ks == 0) {
#pragma unroll
            for (int ni = 0; ni < 2; ++ni) {
                int col = n0 + wc * 32 + ni * 16 + frow;
                float bv0 = bias[(size_t)(2 * pr) * Nc + col];
                float bv1 = bias[(size_t)(2 * pr + 1) * Nc + col];
#pragma unroll
                for (int mi = 0; mi < 4; ++mi) { ac0[mi][ni] = (float4v)(bv0); ac1[mi][ni] = (float4v)(bv1); }
            }
        }
        if (t + 1 < T) stage(t + 1, buf ^ 1);
        const char* Ap = (const char*)As + buf * 16384;
#pragma unroll
        for (int kk = 0; kk < 2; ++kk) {
            short8v av[4], bv0[2], bv1[2];
            const int slot = kk * 4 + fq;
#pragma unroll
            for (int mi = 0; mi < 4; ++mi) {
                int ra = wr * 64 + mi * 16 + frow;
                av[mi] = *(const short8v*)(Ap + ra * 128 + ((slot ^ (ra & 7)) * 16));
            }
#pragma unroll
            for (int ni = 0; ni < 2; ++ni) {
                int rb = wc * 32 + ni * 16 + frow;
                int rboff = rb * 128 + ((slot ^ (rb & 7)) * 16);
                bv0[ni] = *(const short8v*)((const char*)&Bs[buf][0][0] + rboff);
                bv1[ni] = *(const short8v*)((const char*)&Bs[buf][1][0] + rboff);
            }
#pragma unroll
            for (int mi = 0; mi < 4; ++mi)
#pragma unroll
                for (int ni = 0; ni < 2; ++ni) {
                    ac0[mi][ni] = __builtin_amdgcn_mfma_f32_16x16x32_bf16(av[mi], bv0[ni], ac0[mi][ni], 0, 0, 0);
                    ac1[mi][ni] = __builtin_amdgcn_mfma_f32_16x16x32_bf16(av[mi], bv1[ni], ac1[mi][ni], 0, 0, 0);
                }
        }
        if (ks == KS - 1) {
#pragma unroll
            for (int ni = 0; ni < 2; ++ni)
#pragma unroll
                for (int mi = 0; mi < 4; ++mi)
#pragma unroll
                    for (int i = 0; i < 4; ++i) {
                        float mn = fminf(ac0[mi][ni][i], ac1[mi][ni][i]);
                        float mx = fmaxf(ac0[mi][ni][i], ac1[mi][ni][i]);
                        hmn[mi][ni][i] = fminf(hmn[mi][ni][i], mn);
                        hmx[mi][ni][i] = fmaxf(hmx[mi][ni][i], mx);
                    }
        }
        __syncthreads();
        buf ^= 1;
    }

#pragma unroll
    for (int ni = 0; ni < 2; ++ni) {
        int col = n0 + wc * 32 + ni * 16 + frow;
#pragma unroll
        for (int mi = 0; mi < 4; ++mi) {
#pragma unroll
            for (int i = 0; i < 4; ++i) {
                int row = m0 + wr * 64 + mi * 16 + fq * 4 + i;
                float g = fmaxf(gelu_fast(hmn[mi][ni][i]), gelu_fast(hmx[mi][ni][i]));
                out[(size_t)row * Nc + col] = f2bf(g);
            }
        }
    }
}

// ---- dendritic dec (K=256): A-tile RESIDENT in LDS (64 KB), B dual streamed (unchanged) ----
__global__ __launch_bounds__(256, 2) void dendritic_dec_res(const unsigned short* __restrict__ A,
                                                            const unsigned short* __restrict__ WT,
                                                            const float* __restrict__ bias,
                                                            unsigned short* __restrict__ out,
                                                            int M, int Nc, int nb, int nx) {
    constexpr int K = 256;
    __shared__ __align__(16) unsigned short As[128 * 256];
    __shared__ __align__(16) unsigned short Bs[2][64 * 64];
    const int tid = threadIdx.x;
    const int wave = tid >> 6;
    const int lane = tid & 63;

    const int nwg = gridDim.x;
    const int logical = (blockIdx.x & 7) * (nwg >> 3) + (blockIdx.x >> 3);
    const int mblk = logical / nx;
    const int nblk = logical - mblk * nx;
    const int n0 = nblk * 64, m0 = mblk * 128;

    const int wr = wave >> 1, wc = wave & 1;
    const int frow = lane & 15, fq = lane >> 4;

    const char* Ab = (const char*)A;
    const size_t K2 = (size_t)K * 2;
    for (int i = 0; i < 16; ++i) {
        int ch = i * 256 + tid;
        int row = ch >> 5, slot = ch & 31;
        int sslot = (slot & ~7) | ((slot & 7) ^ (row & 7));
        gload_lds16(Ab + (size_t)(m0 + row) * K2 + sslot * 16, (char*)As + i * 4096 + wave * 1024);
    }

    int srB[2], scB[2];
#pragma unroll
    for (int i = 0; i < 2; ++i) {
        int ch = i * 256 + tid;
        srB[i] = ch >> 3;
        scB[i] = ((ch & 7) ^ (srB[i] & 7)) * 16;
    }
    const size_t branchBytes = (size_t)Nc * K2;
    char* lB0 = (char*)&Bs[0][0] + wave * 1024;
    char* lB1 = (char*)&Bs[1][0] + wave * 1024;

    float4v hmn[4][2], hmx[4][2];
#pragma unroll
    for (int mi = 0; mi < 4; ++mi)
#pragma unroll
        for (int ni = 0; ni < 2; ++ni) { hmn[mi][ni] = (float4v)(1e30f); hmx[mi][ni] = (float4v)(-1e30f); }

    const int npair = nb >> 1;
    for (int p = 0; p < npair; ++p) {
        const int b0 = 2 * p, b1 = 2 * p + 1;
        const char* Bb0 = (const char*)WT + (size_t)b0 * branchBytes;
        const char* Bb1 = (const char*)WT + (size_t)b1 * branchBytes;
        float4v ac0[4][2], ac1[4][2];
#pragma unroll
        for (int ni = 0; ni < 2; ++ni) {
            int col = n0 + wc * 32 + ni * 16 + frow;
            float bv0 = bias[(size_t)b0 * Nc + col];
            float bv1 = bias[(size_t)b1 * Nc + col];
#pragma unroll
            for (int mi = 0; mi < 4; ++mi) { ac0[mi][ni] = (float4v)(bv0); ac1[mi][ni] = (float4v)(bv1); }
        }
        for (int k0 = 0; k0 < K; k0 += 64) {
            const size_t kby = (size_t)k0 * 2;
#pragma unroll
            for (int i = 0; i < 2; ++i)
                gload_lds16(Bb0 + (size_t)(n0 + srB[i]) * K2 + kby + scB[i], lB0 + i * 4096);
#pragma unroll
            for (int i = 0; i < 2; ++i)
                gload_lds16(Bb1 + (size_t)(n0 + srB[i]) * K2 + kby + scB[i], lB1 + i * 4096);
            __syncthreads();
#pragma unroll
            for (int kk = 0; kk < 2; ++kk) {
                short8v av[4], bv0[2], bv1[2];
                const int slot = kk * 4 + fq;
#pragma unroll
                for (int mi = 0; mi < 4; ++mi) {
                    int ra = wr * 64 + mi * 16 + frow;
                    int g = (k0 >> 3) + slot;
                    int sl = (g & ~7) | ((g & 7) ^ (ra & 7));
                    av[mi] = *(const short8v*)((const char*)As + ra * 512 + sl * 16);
                }
#pragma unroll
                for (int ni = 0; ni < 2; ++ni) {
                    int rb = wc * 32 + ni * 16 + frow;
                    int rboff = rb * 128 + ((slot ^ (rb & 7)) * 16);
                    bv0[ni] = *(const short8v*)((const char*)&Bs[0][0] + rboff);
                    bv1[ni] = *(const short8v*)((const char*)&Bs[1][0] + rboff);
                }
#pragma unroll
                for (int mi = 0; mi < 4; ++mi)
#pragma unroll
                    for (int ni = 0; ni < 2; ++ni) {
                        ac0[mi][ni] = __builtin_amdgcn_mfma_f32_16x16x32_bf16(av[mi], bv0[ni], ac0[mi][ni], 0, 0, 0);
                        ac1[mi][ni] = __builtin_amdgcn_mfma_f32_16x16x32_bf16(av[mi], bv1[ni], ac1[mi][ni], 0, 0, 0);
                    }
            }
            __syncthreads();
        }
#pragma unroll
        for (int ni = 0; ni < 2; ++ni)
#pragma unroll
            for (int mi = 0; mi < 4; ++mi)
#pragma unroll
                for (int i = 0; i < 4; ++i) {
                    float mn = fminf(ac0[mi][ni][i], ac1[mi][ni][i]);
                    float mx = fmaxf(ac0[mi][ni][i], ac1[mi][ni][i]);
                    hmn[mi][ni][i] = fminf(hmn[mi][ni][i], mn);
                    hmx[mi][ni][i] = fmaxf(hmx[mi][ni][i], mx);
                }
    }

#pragma unroll
    for (int ni = 0; ni < 2; ++ni) {
        int col = n0 + wc * 32 + ni * 16 + frow;
#pragma unroll
        for (int mi = 0; mi < 4; ++mi) {
#pragma unroll
            for (int i = 0; i < 4; ++i) {
                int row = m0 + wr * 64 + mi * 16 + fq * 4 + i;
                float g = fmaxf(gelu_fast(hmn[mi][ni][i]), gelu_fast(hmx[mi][ni][i]));
                out[(size_t)row * Nc + col] = f2bf(g);
            }
        }
    }
}

extern "C" void kernel_launch(void* const* d_in, const int* in_sizes, int n_in,
                              void* d_out, int out_size, void* d_ws, size_t ws_size,
                              hipStream_t stream) {
    const float* x        = (const float*)d_in[0];
    const int*   arows    = (const int*)d_in[1];
    const int*   acols    = (const int*)d_in[2];
    const float* avals    = (const float*)d_in[3];
    const float* basisenc = (const float*)d_in[4];
    const float* ln_g     = (const float*)d_in[5];
    const float* ln_b     = (const float*)d_in[6];
    const float* Wd_enc   = (const float*)d_in[7];
    const float* bd_enc   = (const float*)d_in[8];
    const float* W_mu     = (const float*)d_in[9];
    const float* b_mu     = (const float*)d_in[10];
    const float* W_lv     = (const float*)d_in[11];
    const float* b_lv     = (const float*)d_in[12];
    const float* Wd_dec   = (const float*)d_in[13];
    const float* bd_dec   = (const float*)d_in[14];
    const float* basisdec = (const float*)d_in[15];
    const float* epsin    = (const float*)d_in[16];

    const int N = 16384;
    const int E = in_sizes[1];

    float* ws = (float*)d_ws;
    const size_t A0 = 0;                               // u16 N*512: hx
    const size_t B0 = A0 + (size_t)N * 768;            // u16 N*800: cenc -> [cdec | zb]
    const size_t C0 = B0 + (size_t)N * 400;            // u16: [hbf | encb] -> decb
    const size_t F0 = C0 + (size_t)N * 387;            // u16 weights
    const size_t G0 = F0 + 3100672;                    // CSR

    unsigned short* hx   = (unsigned short*)(ws + A0);
    unsigned short* cenc = (unsigned short*)(ws + B0);
    unsigned short* cdec = (unsigned short*)(ws + B0);
    unsigned short* zb   = cdec + (size_t)N * 544;
    unsigned short* hbf  = (unsigned short*)(ws + C0);
    unsigned short* encb = hbf + (size_t)N * 512;
    unsigned short* decb = (unsigned short*)(ws + C0);
    unsigned short* wF = (unsigned short*)(ws + F0);
    unsigned short* BceT   = wF;                       // 512*800
    unsigned short* BcdT   = BceT + 512 * 800;         // 768*544
    unsigned short* WdencT = BcdT + 768 * 544;         // 20*256*512
    unsigned short* WddecT = WdencT + 20 * 256 * 512;  // 20*512*256
    unsigned short* WmuT   = WddecT + 20 * 512 * 256;  // 256*256
    unsigned short* WlvT   = WmuT + 256 * 256;         // contiguous -> [512,256]
    int*   csr_cnt  = (int*)(ws + G0);
    int*   csr_offs = csr_cnt + N;
    int*   csr_cur  = csr_offs + N + 1;
    int*   csr_col  = csr_cur + N;
    float* csr_val  = (float*)(csr_col + E);

    float* out_recon = (float*)d_out;
    float* out_mu    = out_recon + (size_t)N * 768;
    float* out_lv    = out_mu + (size_t)N * 256;

    // 0) zero hist counts, then MEGA-PREP (packs + wavedec(x) + hist), then scan+scatter
    hipMemsetAsync(csr_cnt, 0, N * sizeof(int), stream);
    {
        const int nwgPrep = 104 + 108 + 640 + 640 + 16 + 16 + (N / 4) + (E + 255) / 256;  // 6644
        prep_kernel<<<nwgPrep, 256, 0, stream>>>(x, basisenc, basisdec, Wd_enc, Wd_dec, W_mu, W_lv,
                                                 arows, E, cenc, BceT, BcdT, WdencT, WddecT, WmuT, WlvT,
                                                 csr_cnt);
    }
    scan_kernel<<<1, 1024, 0, stream>>>(csr_cnt, csr_offs, csr_cur, N, E);
    scatter_kernel<<<(E + 255) / 256, 256, 0, stream>>>(arows, acols, avals, csr_cur, csr_col, csr_val, E);

    // 1) hx = cenc @ BceT^T  [16384,512] bf16, K=800.  nwg = 512
    gemm_mfma<1><<<(512 / 128) * (N / 128), 256, 0, stream>>>(cenc, BceT, nullptr, nullptr, hx, nullptr,
                                                              N, 512, 800, 800, 800, 512, 512 / 128);

    // 2) fused SpMM gather (512-wide) + LayerNorm -> hbf
    spmm_ln<<<N / 4, 256, 0, stream>>>(hx, csr_offs, csr_col, csr_val, ln_g, ln_b, hbf);

    // 3) enc dendritic (K=512): all 20 branches, dual-branch, dbuf 2-phase.  nwg = 512
    dendritic_full<<<4 * (N / 128), 256, 0, stream>>>(hbf, WdencT, bd_enc, encb, N, 256, 512, 20, 4);

    // 4) mu & logvar: single-B GEMM over [WmuT|WlvT] = [512,256], split epilogue.  nwg = 512
    gemm_mfma<2><<<(512 / 128) * (N / 128), 256, 0, stream>>>(encb, WmuT, b_mu, b_lv, out_mu, out_lv,
                                                              N, 512, 256, 256, 256, 256, 512 / 128);

    // 5) z -> bf16
    z_kernel<<<(N * 256 / 4 + 255) / 256, 256, 0, stream>>>(out_mu, out_lv, epsin, zb, N * 256 / 4);

    // 6) dec dendritic (K=256): A-resident LDS.  nwg = 1024
    dendritic_dec_res<<<8 * (N / 128), 256, 0, stream>>>(zb, WddecT, bd_dec, decb, N, 512, 20, 8);

    // 7) fused wavedec-dec -> cdec
    wavedec_dec<<<N / 4, 256, 0, stream>>>(decb, cdec);

    // 8) recon = cdec @ BcdT^T [16384,768], K=544.  nwg = 768
    gemm_mfma<0><<<(768 / 128) * (N / 128), 256, 0, stream>>>(cdec, BcdT, nullptr, nullptr, out_recon, nullptr,
                                                              N, 768, 544, 544, 544, 768, 768 / 128);

    (void)ws_size; (void)out_size; (void)n_in;
}

// Round 19
// 385.363 us; speedup vs baseline: 1.0228x; 1.0228x over previous
//
#include <hip/hip_runtime.h>

typedef __attribute__((ext_vector_type(8))) short short8v;
typedef __attribute__((ext_vector_type(8))) unsigned short ushort8v;
typedef __attribute__((ext_vector_type(4))) float float4v;

__device__ __constant__ float c_LO[8] = {
    -0.010597401784997278f, 0.032883011666982945f, 0.030841381835986965f,
    -0.18703481171888114f, -0.02798376941698385f, 0.6308807679295904f,
    0.7148465705525415f, 0.23037781330885523f};
__device__ __constant__ float c_HI[8] = {
    -0.23037781330885523f, 0.7148465705525415f, -0.6308807679295904f,
    -0.02798376941698385f, 0.18703481171888114f, 0.030841381835986965f,
    -0.032883011666982945f, -0.010597401784997278f};

__device__ __forceinline__ unsigned short f2bf(float f) {
    unsigned u = __builtin_bit_cast(unsigned, f);
    unsigned r = u + 0x7fffu + ((u >> 16) & 1u);
    return (unsigned short)(r >> 16);
}
__device__ __forceinline__ float bf2f(unsigned short u) {
    return __builtin_bit_cast(float, (unsigned)u << 16);
}

__device__ __forceinline__ float gelu_fast(float x) {
    float x3 = x * x * x;
    float y = fmaf(0.044715f, x3, x) * 0.7978845608028654f;
    float t = fminf(fmaxf(y * 2.8853900817779268f, -30.f), 30.f);
    float e = exp2f(t);
    return x * e * __builtin_amdgcn_rcpf(e + 1.0f);
}

__device__ __forceinline__ void gload_lds16(const void* g, void* l) {
    __builtin_amdgcn_global_load_lds(g, l, 16, 0, 0);
}

// ---- one DWT level helpers (pywt symmetric) ----
__device__ __forceinline__ void dwt_lvl(const float* __restrict__ in, int n, float* __restrict__ outA,
                                        unsigned short* __restrict__ outD, int m, int lane) {
    for (int j = lane; j < m; j += 64) {
        float a = 0.f, d = 0.f;
#pragma unroll
        for (int i = 0; i < 8; ++i) {
            int p = 2 * j + 7 - i;
            int q = (p < 6) ? (5 - p) : ((p < n + 6) ? (p - 6) : (2 * n + 5 - p));
            float xv = in[q];
            a = fmaf(c_LO[i], xv, a);
            d = fmaf(c_HI[i], xv, d);
        }
        outA[j] = a;
        outD[j] = f2bf(d);
    }
}
__device__ __forceinline__ void dwt_lvl_final(const float* __restrict__ in, int n, unsigned short* __restrict__ outA,
                                              unsigned short* __restrict__ outD, int m, int lane) {
    for (int j = lane; j < m; j += 64) {
        float a = 0.f, d = 0.f;
#pragma unroll
        for (int i = 0; i < 8; ++i) {
            int p = 2 * j + 7 - i;
            int q = (p < 6) ? (5 - p) : ((p < n + 6) ? (p - 6) : (2 * n + 5 - p));
            float xv = in[q];
            a = fmaf(c_LO[i], xv, a);
            d = fmaf(c_HI[i], xv, d);
        }
        outA[j] = f2bf(a);
        outD[j] = f2bf(d);
    }
}

struct Bounds { int b[6]; };

// ---- pack helpers (LDS-tiled transpose, both sides coalesced) ----
__device__ __forceinline__ void job_pack_w(const float* __restrict__ W, unsigned short* __restrict__ WT,
                                           int br, int k0, int n0, int K, int N, int Kpad,
                                           float (*t)[65], int tid) {
#pragma unroll
    for (int i = 0; i < 16; ++i) {
        int idx = tid + i * 256;
        int kk = idx >> 6, nn = idx & 63;
        int k = k0 + kk;
        t[kk][nn] = (k < K) ? W[((size_t)br * K + k) * N + n0 + nn] : 0.f;
    }
    __syncthreads();
#pragma unroll
    for (int i = 0; i < 16; ++i) {
        int idx = tid + i * 256;
        int nn = idx >> 6, kk = idx & 63;
        int k = k0 + kk;
        if (k < Kpad)
            WT[((size_t)br * N + n0 + nn) * Kpad + k] = f2bf(t[kk][nn]);
    }
}

__device__ __forceinline__ void job_pack_basis(const float* __restrict__ basis, unsigned short* __restrict__ BT,
                                               Bounds bd, int brows, int N, int K, int Kpad,
                                               int k0, int n0, float (*t)[65], int tid) {
#pragma unroll
    for (int i = 0; i < 16; ++i) {
        int idx = tid + i * 256;
        int kk = idx >> 6, nn = idx & 63;
        int k = k0 + kk;
        float v = 0.f;
        if (k < K) {
            int s = 0;
#pragma unroll
            for (int u = 1; u < 5; ++u)
                if (k >= bd.b[u]) s = u;
            int lr = k - bd.b[s];
            v = basis[((size_t)s * brows + lr) * N + n0 + nn];
        }
        t[kk][nn] = v;
    }
    __syncthreads();
#pragma unroll
    for (int i = 0; i < 16; ++i) {
        int idx = tid + i * 256;
        int nn = idx >> 6, kk = idx & 63;
        int k = k0 + kk;
        if (k < Kpad)
            BT[(size_t)(n0 + nn) * Kpad + k] = f2bf(t[kk][nn]);
    }
}

// ---- MEGA-PREP: all packs + wavedec(x) + CSR histogram in ONE kernel ----
__global__ __launch_bounds__(256) void prep_kernel(const float* __restrict__ x,
                                                   const float* __restrict__ basisenc,
                                                   const float* __restrict__ basisdec,
                                                   const float* __restrict__ Wd_enc,
                                                   const float* __restrict__ Wd_dec,
                                                   const float* __restrict__ W_mu,
                                                   const float* __restrict__ W_lv,
                                                   const int* __restrict__ arows, int E,
                                                   unsigned short* __restrict__ cenc,
                                                   unsigned short* __restrict__ BceT,
                                                   unsigned short* __restrict__ BcdT,
                                                   unsigned short* __restrict__ WdencT,
                                                   unsigned short* __restrict__ WddecT,
                                                   unsigned short* __restrict__ WmuT,
                                                   unsigned short* __restrict__ WlvT,
                                                   int* __restrict__ csr_cnt) {
    __shared__ __align__(16) char smem[18688];
    const int bid = blockIdx.x;
    const int tid = threadIdx.x;
    float (*t)[65] = (float(*)[65])smem;

    if (bid < 104) {
        Bounds be = {{0, 54, 108, 210, 407, 794}};
        int b = bid;
        job_pack_basis(basisenc, BceT, be, 768, 512, 794, 800, (b % 13) * 64, (b / 13) * 64, t, tid);
    } else if (bid < 212) {
        Bounds bdd = {{0, 38, 76, 146, 279, 538}};
        int b = bid - 104;
        job_pack_basis(basisdec, BcdT, bdd, 512, 768, 538, 544, (b % 9) * 64, (b / 9) * 64, t, tid);
    } else if (bid < 852) {
        int b = bid - 212;
        int br = b / 32, rem = b % 32;
        job_pack_w(Wd_enc, WdencT, br, (rem % 8) * 64, (rem / 8) * 64, 512, 256, 512, t, tid);
    } else if (bid < 1492) {
        int b = bid - 852;
        int br = b / 32, rem = b % 32;
        job_pack_w(Wd_dec, WddecT, br, (rem % 4) * 64, (rem / 4) * 64, 256, 512, 256, t, tid);
    } else if (bid < 1508) {
        int b = bid - 1492;
        job_pack_w(W_mu, WmuT, 0, (b % 4) * 64, (b / 4) * 64, 256, 256, 256, t, tid);
    } else if (bid < 1524) {
        int b = bid - 1508;
        job_pack_w(W_lv, WlvT, 0, (b % 4) * 64, (b / 4) * 64, 256, 256, 256, t, tid);
    } else if (bid < 5620) {
        const int widx = tid >> 6, lane = tid & 63;
        const int r = (bid - 1524) * 4 + widx;
        float* b0 = (float*)smem + widx * 1168;
        float* b1 = b0 + 768;
        const float* ip = x + (size_t)r * 768;
        for (int i = lane; i < 768; i += 64) b0[i] = ip[i];
        __syncthreads();
        unsigned short* cr = cenc + (size_t)r * 800;
        dwt_lvl(b0, 768, b1, cr + 407, 387, lane);
        __syncthreads();
        dwt_lvl(b1, 387, b0, cr + 210, 197, lane);
        __syncthreads();
        dwt_lvl(b0, 197, b1, cr + 108, 102, lane);
        __syncthreads();
        dwt_lvl_final(b1, 102, cr + 0, cr + 54, 54, lane);
        if (lane < 6) cr[794 + lane] = 0;
    } else {
        int i = (bid - 5620) * 256 + tid;
        if (i < E) atomicAdd(&csr_cnt[arows[i]], 1);
    }
}

// ---------------- CSR build (scan + scatter) ----------------
__global__ __launch_bounds__(1024) void scan_kernel(const int* __restrict__ cnt, int* __restrict__ offs,
                                                    int* __restrict__ cursor, int Nrows, int E) {
    __shared__ int part[1024];
    int tid = threadIdx.x;
    const int per = Nrows / 1024;  // 16
    int base = tid * per;
    int local[16];
    int s = 0;
    for (int i = 0; i < per; ++i) { local[i] = s; s += cnt[base + i]; }
    part[tid] = s;
    __syncthreads();
    for (int off = 1; off < 1024; off <<= 1) {
        int v = part[tid];
        int w = (tid >= off) ? part[tid - off] : 0;
        __syncthreads();
        part[tid] = v + w;
        __syncthreads();
    }
    int pre = (tid == 0) ? 0 : part[tid - 1];
    for (int i = 0; i < per; ++i) {
        int o = pre + local[i];
        offs[base + i] = o;
        cursor[base + i] = o;
    }
    if (tid == 0) offs[Nrows] = E;
}

__global__ void scatter_kernel(const int* __restrict__ rows, const int* __restrict__ cols,
                               const float* __restrict__ vals, int* __restrict__ cursor,
                               int* __restrict__ ccol, float* __restrict__ cval, int E) {
    int i = blockIdx.x * blockDim.x + threadIdx.x;
    if (i >= E) return;
    int r = rows[i];
    int p = atomicAdd(&cursor[r], 1);
    ccol[p] = cols[i];
    cval[p] = vals[i];
}

// ---- FUSED SpMM gather + LayerNorm -> hbf bf16; 4-wide gather pipeline ----
__global__ __launch_bounds__(256) void spmm_ln(const unsigned short* __restrict__ hx,
                                               const int* __restrict__ offs,
                                               const int* __restrict__ ccol,
                                               const float* __restrict__ cval,
                                               const float* __restrict__ g,
                                               const float* __restrict__ b,
                                               unsigned short* __restrict__ hbf) {
    const int widx = threadIdx.x >> 6, lane = threadIdx.x & 63;
    const int r = blockIdx.x * 4 + widx;
    int s = offs[r], e = offs[r + 1];
    float a0[8] = {}, a1[8] = {}, a2[8] = {}, a3[8] = {};
    int j = s;
    for (; j + 3 < e; j += 4) {
        int c0 = ccol[j], c1 = ccol[j + 1], c2 = ccol[j + 2], c3 = ccol[j + 3];
        float v0 = cval[j], v1 = cval[j + 1], v2 = cval[j + 2], v3 = cval[j + 3];
        ushort8v u0 = *(const ushort8v*)(hx + (size_t)c0 * 512 + lane * 8);
        ushort8v u1 = *(const ushort8v*)(hx + (size_t)c1 * 512 + lane * 8);
        ushort8v u2 = *(const ushort8v*)(hx + (size_t)c2 * 512 + lane * 8);
        ushort8v u3 = *(const ushort8v*)(hx + (size_t)c3 * 512 + lane * 8);
#pragma unroll
        for (int t = 0; t < 8; ++t) {
            a0[t] = fmaf(v0, bf2f(u0[t]), a0[t]);
            a1[t] = fmaf(v1, bf2f(u1[t]), a1[t]);
            a2[t] = fmaf(v2, bf2f(u2[t]), a2[t]);
            a3[t] = fmaf(v3, bf2f(u3[t]), a3[t]);
        }
    }
    for (; j < e; ++j) {
        int c0 = ccol[j];
        float v0 = cval[j];
        ushort8v u0 = *(const ushort8v*)(hx + (size_t)c0 * 512 + lane * 8);
#pragma unroll
        for (int t = 0; t < 8; ++t) a0[t] = fmaf(v0, bf2f(u0[t]), a0[t]);
    }
    float acc[8];
#pragma unroll
    for (int t = 0; t < 8; ++t) acc[t] = (a0[t] + a1[t]) + (a2[t] + a3[t]);

    float s1 = 0.f, s2 = 0.f;
#pragma unroll
    for (int t = 0; t < 8; ++t) { s1 += acc[t]; s2 = fmaf(acc[t], acc[t], s2); }
#pragma unroll
    for (int off = 32; off >= 1; off >>= 1) {
        s1 += __shfl_xor(s1, off);
        s2 += __shfl_xor(s2, off);
    }
    float mean = s1 * (1.f / 512.f);
    float var = s2 * (1.f / 512.f) - mean * mean;
    float inv = rsqrtf(var + 1e-5f);
    ushort8v o;
#pragma unroll
    for (int t = 0; t < 8; ++t) {
        int col = lane * 8 + t;
        o[t] = f2bf((acc[t] - mean) * inv * g[col] + b[col]);
    }
    *(ushort8v*)(hbf + (size_t)r * 512 + lane * 8) = o;
}

// ---- FUSED: 4-level wavedec of dec (bf16 in) -> cdec bf16 [N,544] ----
__global__ __launch_bounds__(256) void wavedec_dec(const unsigned short* __restrict__ decb,
                                                   unsigned short* __restrict__ cdec) {
    __shared__ float buf0[4][512];
    __shared__ float buf1[4][272];
    const int widx = threadIdx.x >> 6, lane = threadIdx.x & 63;
    const int r = blockIdx.x * 4 + widx;
    float* b0 = buf0[widx];
    float* b1 = buf1[widx];
    const unsigned short* ip = decb + (size_t)r * 512;
    for (int i = lane; i < 512; i += 64) b0[i] = bf2f(ip[i]);
    __syncthreads();
    unsigned short* cr = cdec + (size_t)r * 544;
    dwt_lvl(b0, 512, b1, cr + 279, 259, lane);
    __syncthreads();
    dwt_lvl(b1, 259, b0, cr + 146, 133, lane);
    __syncthreads();
    dwt_lvl(b0, 133, b1, cr + 76, 70, lane);
    __syncthreads();
    dwt_lvl_final(b1, 70, cr + 0, cr + 38, 38, lane);
    if (lane < 6) cr[538 + lane] = 0;
}

// ---------------- bf16 MFMA GEMM: double-buffered 2-phase (kept — part of r17's win) ----------------
// MODE 0: f32 out. MODE 1: bf16 out. MODE 2: mu/lv split epilogue.
template <int MODE>
__global__ __launch_bounds__(256) void gemm_mfma(const unsigned short* __restrict__ A,
                                                 const unsigned short* __restrict__ BT,
                                                 const float* __restrict__ bias,
                                                 const float* __restrict__ bias2,
                                                 void* __restrict__ Cv, void* __restrict__ Cv2,
                                                 int M, int N, int K, int lda, int ldb, int ldc, int nx) {
    __shared__ __align__(16) unsigned short As[2 * 128 * 32];
    __shared__ __align__(16) unsigned short Bs[2 * 128 * 32];
    const int tid = threadIdx.x;
    const int wave = tid >> 6, lane = tid & 63;
    const int nwg = gridDim.x;
    const int logical = (blockIdx.x & 7) * (nwg >> 3) + (blockIdx.x >> 3);
    const int mblk = logical / nx, nblk = logical - mblk * nx;
    const int m0 = mblk * 128, n0 = nblk * 128;
    const int wr = wave >> 1, wc = wave & 1;
    const int frow = lane & 15, fq = lane >> 4;

    const int off0 = tid * 16;
    const int r0 = off0 >> 6, c0 = off0 & 63;
    const int r1 = (off0 + 4096) >> 6, c1 = (off0 + 4096) & 63;
    const char* Ab = (const char*)A;
    const char* Bb = (const char*)BT;
    size_t gA0 = (size_t)(m0 + r0) * lda * 2 + c0;
    size_t gA1 = (size_t)(m0 + r1) * lda * 2 + c1;
    size_t gB0 = (size_t)(n0 + r0) * ldb * 2 + c0;
    size_t gB1 = (size_t)(n0 + r1) * ldb * 2 + c1;

    const int aoff = (wr * 64 + frow) * 32 + fq * 8;
    const int boff = (wc * 64 + frow) * 32 + fq * 8;
    const int KS = K >> 5;

    auto stage = [&](int ks, int buf) {
        size_t kb2 = (size_t)ks * 64;
        char* lA = (char*)As + buf * 8192 + wave * 1024;
        char* lB = (char*)Bs + buf * 8192 + wave * 1024;
        gload_lds16(Ab + gA0 + kb2, lA);
        gload_lds16(Ab + gA1 + kb2, lA + 4096);
        gload_lds16(Bb + gB0 + kb2, lB);
        gload_lds16(Bb + gB1 + kb2, lB + 4096);
    };

    stage(0, 0);
    __syncthreads();
    float4v acc[4][4] = {};
    int buf = 0;
    for (int ks = 0; ks < KS; ++ks) {
        if (ks + 1 < KS) stage(ks + 1, buf ^ 1);
        const unsigned short* Ap = As + buf * 4096;
        const unsigned short* Bp = Bs + buf * 4096;
        short8v av[4], bv[4];
#pragma unroll
        for (int i = 0; i < 4; ++i) av[i] = *(const short8v*)(Ap + aoff + i * 512);
#pragma unroll
        for (int i = 0; i < 4; ++i) bv[i] = *(const short8v*)(Bp + boff + i * 512);
#pragma unroll
        for (int mi = 0; mi < 4; ++mi)
#pragma unroll
            for (int ni = 0; ni < 4; ++ni)
                acc[mi][ni] = __builtin_amdgcn_mfma_f32_16x16x32_bf16(av[mi], bv[ni], acc[mi][ni], 0, 0, 0);
        __syncthreads();
        buf ^= 1;
    }
#pragma unroll
    for (int ni = 0; ni < 4; ++ni) {
        int col = n0 + wc * 64 + ni * 16 + frow;
#pragma unroll
        for (int mi = 0; mi < 4; ++mi) {
#pragma unroll
            for (int i = 0; i < 4; ++i) {
                int row = m0 + wr * 64 + mi * 16 + fq * 4 + i;
                if (MODE == 0) {
                    ((float*)Cv)[(size_t)row * ldc + col] = acc[mi][ni][i];
                } else if (MODE == 1) {
                    ((unsigned short*)Cv)[(size_t)row * ldc + col] = f2bf(acc[mi][ni][i]);
                } else {
                    bool isMu = col < 256;
                    int coll = col & 255;
                    float bval = isMu ? bias[coll] : bias2[coll];
                    float* dst = (float*)(isMu ? Cv : Cv2);
                    dst[(size_t)row * 256 + coll] = acc[mi][ni][i] + bval;
                }
            }
        }
    }
}

// ---------------- z = mu + eps * exp(0.5*logvar)  -> bf16 ----------------
__global__ void z_kernel(const float* __restrict__ mu, const float* __restrict__ lv,
                         const float* __restrict__ eps, unsigned short* __restrict__ z, int n4) {
    int i = blockIdx.x * blockDim.x + threadIdx.x;
    if (i >= n4) return;
    float4 m = ((const float4*)mu)[i];
    float4 l = ((const float4*)lv)[i];
    float4 e = ((const float4*)eps)[i];
    ushort4 o;
    o.x = f2bf(m.x + e.x * expf(0.5f * l.x));
    o.y = f2bf(m.y + e.y * expf(0.5f * l.y));
    o.z = f2bf(m.z + e.z * expf(0.5f * l.z));
    o.w = f2bf(m.w + e.w * expf(0.5f * l.w));
    ((ushort4*)z)[i] = o;
}

// ---- dendritic enc (K=512): REVERTED to round-16 proven 2-barrier structure ----
__global__ __launch_bounds__(256, 2) void dendritic_full(const unsigned short* __restrict__ A,
                                                         const unsigned short* __restrict__ WT,
                                                         const float* __restrict__ bias,
                                                         unsigned short* __restrict__ out,
                                                         int M, int Nc, int K, int nb, int nx) {
    __shared__ __align__(16) unsigned short As[128 * 64];
    __shared__ __align__(16) unsigned short Bs[2][64 * 64];
    const int tid = threadIdx.x;
    const int wave = tid >> 6;
    const int lane = tid & 63;

    const int nwg = gridDim.x;
    const int logical = (blockIdx.x & 7) * (nwg >> 3) + (blockIdx.x >> 3);
    const int mblk = logical / nx;
    const int nblk = logical - mblk * nx;
    const int n0 = nblk * 64, m0 = mblk * 128;

    const int wr = wave >> 1, wc = wave & 1;
    const int frow = lane & 15, fq = lane >> 4;

    int srA[4], scA[4];
#pragma unroll
    for (int i = 0; i < 4; ++i) {
        int ch = i * 256 + tid;
        srA[i] = ch >> 3;
        scA[i] = ((ch & 7) ^ (srA[i] & 7)) * 16;
    }
    int srB[2], scB[2];
#pragma unroll
    for (int i = 0; i < 2; ++i) {
        int ch = i * 256 + tid;
        srB[i] = ch >> 3;
        scB[i] = ((ch & 7) ^ (srB[i] & 7)) * 16;
    }
    const char* Ab = (const char*)A;
    const size_t K2 = (size_t)K * 2;
    const size_t branchBytes = (size_t)Nc * K2;
    char* lA  = (char*)As + wave * 1024;
    char* lB0 = (char*)&Bs[0][0] + wave * 1024;
    char* lB1 = (char*)&Bs[1][0] + wave * 1024;

    float4v hmn[4][2], hmx[4][2];
#pragma unroll
    for (int mi = 0; mi < 4; ++mi)
#pragma unroll
        for (int ni = 0; ni < 2; ++ni) { hmn[mi][ni] = (float4v)(1e30f); hmx[mi][ni] = (float4v)(-1e30f); }

    const int npair = nb >> 1;
    for (int p = 0; p < npair; ++p) {
        const int b0 = 2 * p, b1 = 2 * p + 1;
        const char* Bb0 = (const char*)WT + (size_t)b0 * branchBytes;
        const char* Bb1 = (const char*)WT + (size_t)b1 * branchBytes;
        float4v ac0[4][2], ac1[4][2];
#pragma unroll
        for (int ni = 0; ni < 2; ++ni) {
            int col = n0 + wc * 32 + ni * 16 + frow;
            float bv0 = bias[(size_t)b0 * Nc + col];
            float bv1 = bias[(size_t)b1 * Nc + col];
#pragma unroll
            for (int mi = 0; mi < 4; ++mi) { ac0[mi][ni] = (float4v)(bv0); ac1[mi][ni] = (float4v)(bv1); }
        }
        for (int k0 = 0; k0 < K; k0 += 64) {
            const size_t kby = (size_t)k0 * 2;
#pragma unroll
            for (int i = 0; i < 4; ++i)
                gload_lds16(Ab + (size_t)(m0 + srA[i]) * K2 + kby + scA[i], lA + i * 4096);
#pragma unroll
            for (int i = 0; i < 2; ++i)
                gload_lds16(Bb0 + (size_t)(n0 + srB[i]) * K2 + kby + scB[i], lB0 + i * 4096);
#pragma unroll
            for (int i = 0; i < 2; ++i)
                gload_lds16(Bb1 + (size_t)(n0 + srB[i]) * K2 + kby + scB[i], lB1 + i * 4096);
            __syncthreads();
#pragma unroll
            for (int kk = 0; kk < 2; ++kk) {
                short8v av[4], bv0[2], bv1[2];
                const int slot = kk * 4 + fq;
#pragma unroll
                for (int mi = 0; mi < 4; ++mi) {
                    int ra = wr * 64 + mi * 16 + frow;
                    av[mi] = *(const short8v*)((const char*)As + ra * 128 + ((slot ^ (ra & 7)) * 16));
                }
#pragma unroll
                for (int ni = 0; ni < 2; ++ni) {
                    int rb = wc * 32 + ni * 16 + frow;
                    int rboff = rb * 128 + ((slot ^ (rb & 7)) * 16);
                    bv0[ni] = *(const short8v*)((const char*)&Bs[0][0] + rboff);
                    bv1[ni] = *(const short8v*)((const char*)&Bs[1][0] + rboff);
                }
#pragma unroll
                for (int mi = 0; mi < 4; ++mi)
#pragma unroll
                    for (int ni = 0; ni < 2; ++ni) {
                        ac0[mi][ni] = __builtin_amdgcn_mfma_f32_16x16x32_bf16(av[mi], bv0[ni], ac0[mi][ni], 0, 0, 0);
                        ac1[mi][ni] = __builtin_amdgcn_mfma_f32_16x16x32_bf16(av[mi], bv1[ni], ac1[mi][ni], 0, 0, 0);
                    }
            }
            __syncthreads();
        }
#pragma unroll
        for (int ni = 0; ni < 2; ++ni)
#pragma unroll
            for (int mi = 0; mi < 4; ++mi)
#pragma unroll
                for (int i = 0; i < 4; ++i) {
                    float mn = fminf(ac0[mi][ni][i], ac1[mi][ni][i]);
                    float mx = fmaxf(ac0[mi][ni][i], ac1[mi][ni][i]);
                    hmn[mi][ni][i] = fminf(hmn[mi][ni][i], mn);
                    hmx[mi][ni][i] = fmaxf(hmx[mi][ni][i], mx);
                }
    }

#pragma unroll
    for (int ni = 0; ni < 2; ++ni) {
        int col = n0 + wc * 32 + ni * 16 + frow;
#pragma unroll
        for (int mi = 0; mi < 4; ++mi) {
#pragma unroll
            for (int i = 0; i < 4; ++i) {
                int row = m0 + wr * 64 + mi * 16 + fq * 4 + i;
                float g = fmaxf(gelu_fast(hmn[mi][ni][i]), gelu_fast(hmx[mi][ni][i]));
                out[(size_t)row * Nc + col] = f2bf(g);
            }
        }
    }
}

// ---- dendritic dec (K=256): A-tile RESIDENT in LDS (64 KB), B dual streamed ----
__global__ __launch_bounds__(256, 2) void dendritic_dec_res(const unsigned short* __restrict__ A,
                                                            const unsigned short* __restrict__ WT,
                                                            const float* __restrict__ bias,
                                                            unsigned short* __restrict__ out,
                                                            int M, int Nc, int nb, int nx) {
    constexpr int K = 256;
    __shared__ __align__(16) unsigned short As[128 * 256];
    __shared__ __align__(16) unsigned short Bs[2][64 * 64];
    const int tid = threadIdx.x;
    const int wave = tid >> 6;
    const int lane = tid & 63;

    const int nwg = gridDim.x;
    const int logical = (blockIdx.x & 7) * (nwg >> 3) + (blockIdx.x >> 3);
    const int mblk = logical / nx;
    const int nblk = logical - mblk * nx;
    const int n0 = nblk * 64, m0 = mblk * 128;

    const int wr = wave >> 1, wc = wave & 1;
    const int frow = lane & 15, fq = lane >> 4;

    const char* Ab = (const char*)A;
    const size_t K2 = (size_t)K * 2;
    for (int i = 0; i < 16; ++i) {
        int ch = i * 256 + tid;
        int row = ch >> 5, slot = ch & 31;
        int sslot = (slot & ~7) | ((slot & 7) ^ (row & 7));
        gload_lds16(Ab + (size_t)(m0 + row) * K2 + sslot * 16, (char*)As + i * 4096 + wave * 1024);
    }

    int srB[2], scB[2];
#pragma unroll
    for (int i = 0; i < 2; ++i) {
        int ch = i * 256 + tid;
        srB[i] = ch >> 3;
        scB[i] = ((ch & 7) ^ (srB[i] & 7)) * 16;
    }
    const size_t branchBytes = (size_t)Nc * K2;
    char* lB0 = (char*)&Bs[0][0] + wave * 1024;
    char* lB1 = (char*)&Bs[1][0] + wave * 1024;

    float4v hmn[4][2], hmx[4][2];
#pragma unroll
    for (int mi = 0; mi < 4; ++mi)
#pragma unroll
        for (int ni = 0; ni < 2; ++ni) { hmn[mi][ni] = (float4v)(1e30f); hmx[mi][ni] = (float4v)(-1e30f); }

    const int npair = nb >> 1;
    for (int p = 0; p < npair; ++p) {
        const int b0 = 2 * p, b1 = 2 * p + 1;
        const char* Bb0 = (const char*)WT + (size_t)b0 * branchBytes;
        const char* Bb1 = (const char*)WT + (size_t)b1 * branchBytes;
        float4v ac0[4][2], ac1[4][2];
#pragma unroll
        for (int ni = 0; ni < 2; ++ni) {
            int col = n0 + wc * 32 + ni * 16 + frow;
            float bv0 = bias[(size_t)b0 * Nc + col];
            float bv1 = bias[(size_t)b1 * Nc + col];
#pragma unroll
            for (int mi = 0; mi < 4; ++mi) { ac0[mi][ni] = (float4v)(bv0); ac1[mi][ni] = (float4v)(bv1); }
        }
        for (int k0 = 0; k0 < K; k0 += 64) {
            const size_t kby = (size_t)k0 * 2;
#pragma unroll
            for (int i = 0; i < 2; ++i)
                gload_lds16(Bb0 + (size_t)(n0 + srB[i]) * K2 + kby + scB[i], lB0 + i * 4096);
#pragma unroll
            for (int i = 0; i < 2; ++i)
                gload_lds16(Bb1 + (size_t)(n0 + srB[i]) * K2 + kby + scB[i], lB1 + i * 4096);
            __syncthreads();
#pragma unroll
            for (int kk = 0; kk < 2; ++kk) {
                short8v av[4], bv0[2], bv1[2];
                const int slot = kk * 4 + fq;
#pragma unroll
                for (int mi = 0; mi < 4; ++mi) {
                    int ra = wr * 64 + mi * 16 + frow;
                    int g = (k0 >> 3) + slot;
                    int sl = (g & ~7) | ((g & 7) ^ (ra & 7));
                    av[mi] = *(const short8v*)((const char*)As + ra * 512 + sl * 16);
                }
#pragma unroll
                for (int ni = 0; ni < 2; ++ni) {
                    int rb = wc * 32 + ni * 16 + frow;
                    int rboff = rb * 128 + ((slot ^ (rb & 7)) * 16);
                    bv0[ni] = *(const short8v*)((const char*)&Bs[0][0] + rboff);
                    bv1[ni] = *(const short8v*)((const char*)&Bs[1][0] + rboff);
                }
#pragma unroll
                for (int mi = 0; mi < 4; ++mi)
#pragma unroll
                    for (int ni = 0; ni < 2; ++ni) {
                        ac0[mi][ni] = __builtin_amdgcn_mfma_f32_16x16x32_bf16(av[mi], bv0[ni], ac0[mi][ni], 0, 0, 0);
                        ac1[mi][ni] = __builtin_amdgcn_mfma_f32_16x16x32_bf16(av[mi], bv1[ni], ac1[mi][ni], 0, 0, 0);
                    }
            }
            __syncthreads();
        }
#pragma unroll
        for (int ni = 0; ni < 2; ++ni)
#pragma unroll
            for (int mi = 0; mi < 4; ++mi)
#pragma unroll
                for (int i = 0; i < 4; ++i) {
                    float mn = fminf(ac0[mi][ni][i], ac1[mi][ni][i]);
                    float mx = fmaxf(ac0[mi][ni][i], ac1[mi][ni][i]);
                    hmn[mi][ni][i] = fminf(hmn[mi][ni][i], mn);
                    hmx[mi][ni][i] = fmaxf(hmx[mi][ni][i], mx);
                }
    }

#pragma unroll
    for (int ni = 0; ni < 2; ++ni) {
        int col = n0 + wc * 32 + ni * 16 + frow;
#pragma unroll
        for (int mi = 0; mi < 4; ++mi) {
#pragma unroll
            for (int i = 0; i < 4; ++i) {
                int row = m0 + wr * 64 + mi * 16 + fq * 4 + i;
                float g = fmaxf(gelu_fast(hmn[mi][ni][i]), gelu_fast(hmx[mi][ni][i]));
                out[(size_t)row * Nc + col] = f2bf(g);
            }
        }
    }
}

extern "C" void kernel_launch(void* const* d_in, const int* in_sizes, int n_in,
                              void* d_out, int out_size, void* d_ws, size_t ws_size,
                              hipStream_t stream) {
    const float* x        = (const float*)d_in[0];
    const int*   arows    = (const int*)d_in[1];
    const int*   acols    = (const int*)d_in[2];
    const float* avals    = (const float*)d_in[3];
    const float* basisenc = (const float*)d_in[4];
    const float* ln_g     = (const float*)d_in[5];
    const float* ln_b     = (const float*)d_in[6];
    const float* Wd_enc   = (const float*)d_in[7];
    const float* bd_enc   = (const float*)d_in[8];
    const float* W_mu     = (const float*)d_in[9];
    const float* b_mu     = (const float*)d_in[10];
    const float* W_lv     = (const float*)d_in[11];
    const float* b_lv     = (const float*)d_in[12];
    const float* Wd_dec   = (const float*)d_in[13];
    const float* bd_dec   = (const float*)d_in[14];
    const float* basisdec = (const float*)d_in[15];
    const float* epsin    = (const float*)d_in[16];

    const int N = 16384;
    const int E = in_sizes[1];

    float* ws = (float*)d_ws;
    const size_t A0 = 0;                               // u16 N*512: hx
    const size_t B0 = A0 + (size_t)N * 768;            // u16 N*800: cenc -> [cdec | zb]
    const size_t C0 = B0 + (size_t)N * 400;            // u16: [hbf | encb] -> decb
    const size_t F0 = C0 + (size_t)N * 387;            // u16 weights
    const size_t G0 = F0 + 3100672;                    // CSR

    unsigned short* hx   = (unsigned short*)(ws + A0);
    unsigned short* cenc = (unsigned short*)(ws + B0);
    unsigned short* cdec = (unsigned short*)(ws + B0);
    unsigned short* zb   = cdec + (size_t)N * 544;
    unsigned short* hbf  = (unsigned short*)(ws + C0);
    unsigned short* encb = hbf + (size_t)N * 512;
    unsigned short* decb = (unsigned short*)(ws + C0);
    unsigned short* wF = (unsigned short*)(ws + F0);
    unsigned short* BceT   = wF;                       // 512*800
    unsigned short* BcdT   = BceT + 512 * 800;         // 768*544
    unsigned short* WdencT = BcdT + 768 * 544;         // 20*256*512
    unsigned short* WddecT = WdencT + 20 * 256 * 512;  // 20*512*256
    unsigned short* WmuT   = WddecT + 20 * 512 * 256;  // 256*256
    unsigned short* WlvT   = WmuT + 256 * 256;         // contiguous -> [512,256]
    int*   csr_cnt  = (int*)(ws + G0);
    int*   csr_offs = csr_cnt + N;
    int*   csr_cur  = csr_offs + N + 1;
    int*   csr_col  = csr_cur + N;
    float* csr_val  = (float*)(csr_col + E);

    float* out_recon = (float*)d_out;
    float* out_mu    = out_recon + (size_t)N * 768;
    float* out_lv    = out_mu + (size_t)N * 256;

    // 0) zero hist counts, then MEGA-PREP (packs + wavedec(x) + hist), then scan+scatter
    hipMemsetAsync(csr_cnt, 0, N * sizeof(int), stream);
    {
        const int nwgPrep = 104 + 108 + 640 + 640 + 16 + 16 + (N / 4) + (E + 255) / 256;  // 6644
        prep_kernel<<<nwgPrep, 256, 0, stream>>>(x, basisenc, basisdec, Wd_enc, Wd_dec, W_mu, W_lv,
                                                 arows, E, cenc, BceT, BcdT, WdencT, WddecT, WmuT, WlvT,
                                                 csr_cnt);
    }
    scan_kernel<<<1, 1024, 0, stream>>>(csr_cnt, csr_offs, csr_cur, N, E);
    scatter_kernel<<<(E + 255) / 256, 256, 0, stream>>>(arows, acols, avals, csr_cur, csr_col, csr_val, E);

    // 1) hx = cenc @ BceT^T  [16384,512] bf16, K=800.  nwg = 512
    gemm_mfma<1><<<(512 / 128) * (N / 128), 256, 0, stream>>>(cenc, BceT, nullptr, nullptr, hx, nullptr,
                                                              N, 512, 800, 800, 800, 512, 512 / 128);

    // 2) fused SpMM gather (512-wide) + LayerNorm -> hbf
    spmm_ln<<<N / 4, 256, 0, stream>>>(hx, csr_offs, csr_col, csr_val, ln_g, ln_b, hbf);

    // 3) enc dendritic (K=512): all 20 branches, dual-branch (r16 proven).  nwg = 512
    dendritic_full<<<4 * (N / 128), 256, 0, stream>>>(hbf, WdencT, bd_enc, encb, N, 256, 512, 20, 4);

    // 4) mu & logvar: single-B GEMM over [WmuT|WlvT] = [512,256], split epilogue.  nwg = 512
    gemm_mfma<2><<<(512 / 128) * (N / 128), 256, 0, stream>>>(encb, WmuT, b_mu, b_lv, out_mu, out_lv,
                                                              N, 512, 256, 256, 256, 256, 512 / 128);

    // 5) z -> bf16
    z_kernel<<<(N * 256 / 4 + 255) / 256, 256, 0, stream>>>(out_mu, out_lv, epsin, zb, N * 256 / 4);

    // 6) dec dendritic (K=256): A-resident LDS.  nwg = 1024
    dendritic_dec_res<<<8 * (N / 128), 256, 0, stream>>>(zb, WddecT, bd_dec, decb, N, 512, 20, 8);

    // 7) fused wavedec-dec -> cdec
    wavedec_dec<<<N / 4, 256, 0, stream>>>(decb, cdec);

    // 8) recon = cdec @ BcdT^T [16384,768], K=544.  nwg = 768
    gemm_mfma<0><<<(768 / 128) * (N / 128), 256, 0, stream>>>(cdec, BcdT, nullptr, nullptr, out_recon, nullptr,
                                                              N, 768, 544, 544, 544, 768, 768 / 128);

    (void)ws_size; (void)out_size; (void)n_in;
}